// Round 9
// baseline (798.834 us; speedup 1.0000x reference)
//
#include <hip/hip_runtime.h>

typedef __attribute__((ext_vector_type(8))) short bfrag;   // 8 bf16 = 4 VGPRs
typedef __attribute__((ext_vector_type(4))) float f4;      // MFMA 16x16 acc

__device__ __forceinline__ unsigned short f2b(float f) {
  unsigned int u = __builtin_bit_cast(unsigned int, f);
  u = (u + 0x7fffu + ((u >> 16) & 1u)) >> 16;   // RNE f32->bf16
  return (unsigned short)u;
}
__device__ __forceinline__ float b2f(unsigned short s) {
  unsigned int u = ((unsigned int)s) << 16;
  return __builtin_bit_cast(float, u);
}
__device__ __forceinline__ float relu(float v) { return v > 0.f ? v : 0.f; }

// ---- stage a 64x128 f32 tile into LDS bf16, swizzled
__device__ __forceinline__ void stage_A(char* dst, const float* s0, long r0, long maxRow) {
  const int tid = threadIdx.x;
#pragma unroll
  for (int i = 0; i < 4; ++i) {
    int ch = tid + (i << 8);
    int row = ch >> 4, kg = ch & 15;
    long gr = r0 + row;
    float v[8];
    if (gr < maxRow) {
      const float4* p = (const float4*)(s0 + gr * 128 + kg * 8);
      float4 a = p[0], b = p[1];
      v[0] = a.x; v[1] = a.y; v[2] = a.z; v[3] = a.w;
      v[4] = b.x; v[5] = b.y; v[6] = b.z; v[7] = b.w;
    } else {
#pragma unroll
      for (int j = 0; j < 8; ++j) v[j] = 0.f;
    }
    union { unsigned short h[8]; uint4 u; } pk;
#pragma unroll
    for (int j = 0; j < 8; ++j) pk.h[j] = f2b(v[j]);
    *(uint4*)(dst + (((row << 8) + (kg << 4)) ^ ((row & 7) << 4))) = pk.u;
  }
}

// ---- stage bf16(hb) + f32(ag) sum into LDS bf16, swizzled
__device__ __forceinline__ void stage_A_mix(char* dst, const unsigned short* hb,
                                            const float* ag, long r0, long maxRow) {
  const int tid = threadIdx.x;
#pragma unroll
  for (int i = 0; i < 4; ++i) {
    int ch = tid + (i << 8);
    int row = ch >> 4, kg = ch & 15;
    long gr = r0 + row;
    union { unsigned short h[8]; uint4 u; } pk;
    if (gr < maxRow) {
      uint4 hv = *(const uint4*)(hb + gr * 128 + kg * 8);
      const float4* q = (const float4*)(ag + gr * 128 + kg * 8);
      float4 c = q[0], d = q[1];
      pk.h[0] = f2b(b2f((unsigned short)hv.x) + c.x);
      pk.h[1] = f2b(b2f((unsigned short)(hv.x >> 16)) + c.y);
      pk.h[2] = f2b(b2f((unsigned short)hv.y) + c.z);
      pk.h[3] = f2b(b2f((unsigned short)(hv.y >> 16)) + c.w);
      pk.h[4] = f2b(b2f((unsigned short)hv.z) + d.x);
      pk.h[5] = f2b(b2f((unsigned short)(hv.z >> 16)) + d.y);
      pk.h[6] = f2b(b2f((unsigned short)hv.w) + d.z);
      pk.h[7] = f2b(b2f((unsigned short)(hv.w >> 16)) + d.w);
    } else {
      pk.u = uint4{0, 0, 0, 0};
    }
    *(uint4*)(dst + (((row << 8) + (kg << 4)) ^ ((row & 7) << 4))) = pk.u;
  }
}

// ---- stage 128x128 bf16 weight tile into 32KB LDS, swizzled
__device__ __forceinline__ void stage_W(char* dst, const unsigned short* src,
                                        int rowStride, int kOff) {
  const int tid = threadIdx.x;
#pragma unroll
  for (int i = 0; i < 8; ++i) {
    int ch = tid + (i << 8);
    int col = ch >> 4, kg = ch & 15;
    uint4 u = *(const uint4*)(src + (size_t)col * rowStride + kOff + kg * 8);
    *(uint4*)(dst + (((col << 8) + (kg << 4)) ^ ((col & 7) << 4))) = u;
  }
}

// ---- stage 128col x 64K bf16 weight K-half into 16KB LDS, swizzled 128B rows
__device__ __forceinline__ void stage_Wh(char* dst, const unsigned short* src,
                                         int rowStride, int kOff) {
  const int tid = threadIdx.x;
#pragma unroll
  for (int i = 0; i < 4; ++i) {
    int ch = tid + (i << 8);
    int c = ch >> 3, kg = ch & 7;
    uint4 u = *(const uint4*)(src + (size_t)c * rowStride + kOff + kg * 8);
    *(uint4*)(dst + (((c << 7) + (kg << 4)) ^ ((c & 7) << 4))) = u;
  }
}

// ---- per-wave 32x64 tile matmul over K=128 (full-K weight tile)
__device__ __forceinline__ void mm(const char* A, const char* W, int wm, int wn,
                                   int lane, f4 acc[2][4]) {
#pragma unroll
  for (int kk = 0; kk < 4; ++kk) {
    bfrag a[2], b[4];
#pragma unroll
    for (int rt = 0; rt < 2; ++rt) {
      int row = (wm << 5) + (rt << 4) + (lane & 15);
      a[rt] = *(const bfrag*)(A + (((row << 8) + (kk << 6) + ((lane >> 4) << 4)) ^ ((row & 7) << 4)));
    }
#pragma unroll
    for (int ct = 0; ct < 4; ++ct) {
      int col = (wn << 6) + (ct << 4) + (lane & 15);
      b[ct] = *(const bfrag*)(W + (((col << 8) + (kk << 6) + ((lane >> 4) << 4)) ^ ((col & 7) << 4)));
    }
#pragma unroll
    for (int rt = 0; rt < 2; ++rt)
#pragma unroll
      for (int ct = 0; ct < 4; ++ct)
        acc[rt][ct] = __builtin_amdgcn_mfma_f32_16x16x32_bf16(a[rt], b[ct], acc[rt][ct], 0, 0, 0);
  }
}

// ---- per-wave 32x64 over one 64-wide K-half (16KB weight tile), accumulate
__device__ __forceinline__ void mm_h(const char* A, const char* W, int wm, int wn,
                                     int lane, f4 acc[2][4], int kh) {
#pragma unroll
  for (int kk2 = 0; kk2 < 2; ++kk2) {
    int kA = (kh << 1) + kk2;
    bfrag a[2], b[4];
#pragma unroll
    for (int rt = 0; rt < 2; ++rt) {
      int row = (wm << 5) + (rt << 4) + (lane & 15);
      a[rt] = *(const bfrag*)(A + (((row << 8) + (kA << 6) + ((lane >> 4) << 4)) ^ ((row & 7) << 4)));
    }
#pragma unroll
    for (int ct = 0; ct < 4; ++ct) {
      int col = (wn << 6) + (ct << 4) + (lane & 15);
      b[ct] = *(const bfrag*)(W + (((col << 7) + (kk2 << 6) + ((lane >> 4) << 4)) ^ ((col & 7) << 4)));
    }
#pragma unroll
    for (int rt = 0; rt < 2; ++rt)
#pragma unroll
      for (int ct = 0; ct < 4; ++ct)
        acc[rt][ct] = __builtin_amdgcn_mfma_f32_16x16x32_bf16(a[rt], b[ct], acc[rt][ct], 0, 0, 0);
  }
}

// ---- dump one wave's acc (rows of its wm-half) into 16KB f32 half-stage
__device__ __forceinline__ void dump_half(char* Wl, const f4 acc[2][4], int lane, int wn) {
#pragma unroll
  for (int ct = 0; ct < 4; ++ct) {
    int col = (wn << 6) + (ct << 4) + (lane & 15);
#pragma unroll
    for (int rt = 0; rt < 2; ++rt)
#pragma unroll
      for (int j = 0; j < 4; ++j) {
        int lr = (rt << 4) + ((lane >> 4) << 2) + j;
        *(float*)(Wl + (((lr << 9) + (col << 2)) ^ ((lr & 7) << 4))) = acc[rt][ct][j];
      }
  }
}

// ---- dump full 64-row acc into 32KB f32 stage
__device__ __forceinline__ void dump_full(char* stg, const f4 acc[2][4], int lane, int wm, int wn) {
#pragma unroll
  for (int ct = 0; ct < 4; ++ct) {
    int col = (wn << 6) + (ct << 4) + (lane & 15);
#pragma unroll
    for (int rt = 0; rt < 2; ++rt)
#pragma unroll
      for (int j = 0; j < 4; ++j) {
        int rl = (wm << 5) + (rt << 4) + ((lane >> 4) << 2) + j;
        *(float*)(stg + (((rl << 9) + (col << 2)) ^ ((rl & 7) << 4))) = acc[rt][ct][j];
      }
  }
}

// ---- weight prep: f32 [in][out] -> bf16 [out][in]
__global__ void k_prep(const float* __restrict__ Wq, const float* __restrict__ Wk,
                       const float* __restrict__ Wv, const float* __restrict__ We1,
                       const float* __restrict__ We2, const float* __restrict__ Wh,
                       const float* __restrict__ Wf1, const float* __restrict__ Wf2,
                       unsigned short* __restrict__ wt) {
  int b = blockIdx.x, t = threadIdx.x;
  if (b < 384) {
    int m = b >> 6;
    const float* tbl[6] = {Wq, Wk, Wv, We1, We2, Wh};
    const float* src = tbl[m];
    int local = ((b & 63) << 8) + t;
    int n = local >> 7, k = local & 127;
    wt[m * 16384 + local] = f2b(src[k * 128 + n]);
  } else if (b < 512) {
    int local = ((b - 384) << 8) + t;   // Wf1T [256][128]
    int n = local >> 7, k = local & 127;
    wt[98304 + local] = f2b(Wf1[k * 256 + n]);
  } else {
    int local = ((b - 512) << 8) + t;   // Wf2T [128][256]
    int n = local >> 8, k = local & 255;
    wt[131072 + local] = f2b(Wf2[k * 128 + n]);
  }
}

// ---- CSR build ----
__global__ void k_deg(const int* __restrict__ ei, int* __restrict__ deg, long E) {
  long g = (long)blockIdx.x * 256 + threadIdx.x;
  if (g < E) atomicAdd(deg + ei[E + g], 1);
}

__global__ void k_scanA(const int* __restrict__ deg, int* __restrict__ ex,
                        int* __restrict__ bsum, int n) {
  __shared__ int s[256];
  int t = threadIdx.x; int g = blockIdx.x * 256 + t;
  int v = (g < n) ? deg[g] : 0;
  int val = v;
  s[t] = val; __syncthreads();
#pragma unroll
  for (int o = 1; o < 256; o <<= 1) {
    int u = (t >= o) ? s[t - o] : 0;
    __syncthreads();
    val += u; s[t] = val;
    __syncthreads();
  }
  if (g < n) ex[g] = val - v;
  if (t == 255) bsum[blockIdx.x] = val;
}

__global__ void k_scanB(int* __restrict__ bsum, int nb) {
  __shared__ int s[1024];
  int t = threadIdx.x;
  int v = (t < nb) ? bsum[t] : 0;
  int val = v;
  s[t] = val; __syncthreads();
#pragma unroll
  for (int o = 1; o < 1024; o <<= 1) {
    int u = (t >= o) ? s[t - o] : 0;
    __syncthreads();
    val += u; s[t] = val;
    __syncthreads();
  }
  if (t < nb) bsum[t] = val - v;
}

__global__ void k_scanC(const int* __restrict__ ex, const int* __restrict__ bsum,
                        int* __restrict__ off, int* __restrict__ cursor, int n) {
  int g = blockIdx.x * 256 + threadIdx.x;
  if (g < n) {
    int o = ex[g] + bsum[blockIdx.x];
    off[g] = o; cursor[g] = o;
  }
}

__global__ void k_fill(const int* __restrict__ ei, int* __restrict__ cursor,
                       int* __restrict__ eidx, long E) {
  long g = (long)blockIdx.x * 256 + threadIdx.x;
  if (g < E) {
    int pos = atomicAdd(cursor + ei[E + g], 1);
    eidx[pos] = (int)g;
  }
}

// ---- kernel 1: Q,K,V -> h = relu(Q*K) (bf16), hpvb = bf16(h+V)
__global__ __launch_bounds__(256, 2) void k_nodes1(
    const float* __restrict__ x, const float* __restrict__ ph,
    const float* __restrict__ bq, const float* __restrict__ bk,
    const float* __restrict__ bv, const unsigned short* __restrict__ wt,
    unsigned short* __restrict__ hbf, unsigned short* __restrict__ hpvb, long N) {
  extern __shared__ char sm[];
  char* Ax = sm;            // 16KB (x tile, then h out)
  char* Aph = sm + 16384;   // 16KB (ph tile, then h+v out)
  char* Wl = sm + 32768;    // 32KB
  long n0 = (long)blockIdx.x * 64;
  const int tid = threadIdx.x, lane = tid & 63, w = tid >> 6, wm = w >> 1, wn = w & 1;
  const int team = tid >> 5, c0 = (tid & 31) << 2;
  stage_A(Ax, x, n0, N);
  stage_A(Aph, ph, n0, N);
  stage_W(Wl, wt + 0, 128, 0);
  __syncthreads();
  f4 accQ[2][4] = {};
  mm(Ax, Wl, wm, wn, lane, accQ);
  __syncthreads();
  stage_W(Wl, wt + 16384, 128, 0);
  __syncthreads();
  f4 accK[2][4] = {};
  mm(Aph, Wl, wm, wn, lane, accK);
  __syncthreads();
  stage_W(Wl, wt + 32768, 128, 0);
  __syncthreads();
  f4 accV[2][4] = {};
  mm(Aph, Wl, wm, wn, lane, accV);
  __syncthreads();
  // epilogue: h -> Ax (bf16 swizzled), h+v -> Aph (bf16 swizzled)
#pragma unroll
  for (int ct = 0; ct < 4; ++ct) {
    int col = (wn << 6) + (ct << 4) + (lane & 15);
    float vbq = bq[col], vbk = bk[col], vbv = bv[col];
#pragma unroll
    for (int rt = 0; rt < 2; ++rt)
#pragma unroll
      for (int j = 0; j < 4; ++j) {
        int rl = (wm << 5) + (rt << 4) + ((lane >> 4) << 2) + j;
        float q = accQ[rt][ct][j] + vbq;
        float k = accK[rt][ct][j] + vbk;
        float v = accV[rt][ct][j] + vbv;
        float h = relu(q * k);
        *(unsigned short*)(Ax + (((rl << 8) + (col << 1)) ^ ((rl & 7) << 4))) = f2b(h);
        *(unsigned short*)(Aph + (((rl << 8) + (col << 1)) ^ ((rl & 7) << 4))) = f2b(h + v);
      }
  }
  __syncthreads();
#pragma unroll
  for (int it = 0; it < 8; ++it) {
    int r = team + (it << 3);
    long row = n0 + r;
    if (row < N) {
      uint2 hb = *(const uint2*)(Ax + (((r << 8) + (c0 << 1)) ^ ((r & 7) << 4)));
      uint2 hv = *(const uint2*)(Aph + (((r << 8) + (c0 << 1)) ^ ((r & 7) << 4)));
      *(uint2*)(hbf + row * 128 + c0) = hb;
      *(uint2*)(hpvb + row * 128 + c0) = hv;
    }
  }
}

// ---- kernel 2: edge MLP + gather; pe kept in registers; 32.3KB LDS -> 4 blocks/CU
__global__ __launch_bounds__(256, 4) void k_edges(
    const float* __restrict__ ea, const float* __restrict__ pe,
    const float* __restrict__ be1, const float* __restrict__ be2,
    const unsigned short* __restrict__ wt, const int* __restrict__ ei,
    const unsigned short* __restrict__ hbf, unsigned short* __restrict__ msg,
    float* __restrict__ eout, long E) {
  extern __shared__ char sm[];
  char* A = sm;          // 16KB swizzled bf16 [64][128]
  char* Wl = sm + 16384; // 16KB weight K-half / f32 transition half-stage
  char* stg = sm;        // 32KB final f32 stage (overlays A+Wl)
  int* srcI = (int*)(sm + 32768);   // 256B
  const int tid = threadIdx.x;
  const int team = tid >> 5, c0 = (tid & 31) << 2;
  long e0 = (long)blockIdx.x * 64;
  if (tid < 64) srcI[tid] = (e0 + tid < E) ? ei[e0 + tid] : 0;

  // stage A = bf16(ea+pe) swizzled, team/c0 mapping; keep pe bf16 in registers
  uint2 peR[8];
#pragma unroll
  for (int it = 0; it < 8; ++it) {
    int r = team + (it << 3);
    long ge = e0 + r;
    float4 av = make_float4(0.f, 0.f, 0.f, 0.f), pv = av;
    if (ge < E) {
      av = *(const float4*)(ea + ge * 128 + c0);
      pv = *(const float4*)(pe + ge * 128 + c0);
    }
    peR[it].x = (unsigned)f2b(pv.x) | ((unsigned)f2b(pv.y) << 16);
    peR[it].y = (unsigned)f2b(pv.z) | ((unsigned)f2b(pv.w) << 16);
    uint2 s;
    s.x = (unsigned)f2b(av.x + pv.x) | ((unsigned)f2b(av.y + pv.y) << 16);
    s.y = (unsigned)f2b(av.z + pv.z) | ((unsigned)f2b(av.w + pv.w) << 16);
    *(uint2*)(A + (((r << 8) + (c0 << 1)) ^ ((r & 7) << 4))) = s;
  }
  stage_Wh(Wl, wt + 49152, 128, 0);   // We1T K 0..63
  __syncthreads();
  const int lane = tid & 63, w = tid >> 6, wm = w >> 1, wn = w & 1;
  f4 acc[2][4] = {};
  mm_h(A, Wl, wm, wn, lane, acc, 0);
  __syncthreads();
  stage_Wh(Wl, wt + 49152, 128, 64);  // We1T K 64..127
  __syncthreads();
  mm_h(A, Wl, wm, wn, lane, acc, 1);
  __syncthreads();
  // transition: A <- bf16(relu(acc+be1) + pe), two 32-row halves staged through Wl
  const float4 vb1 = *(const float4*)(be1 + c0);
#pragma unroll
  for (int h = 0; h < 2; ++h) {
    if (wm == h) dump_half(Wl, acc, lane, wn);
    __syncthreads();
#pragma unroll
    for (int it = 0; it < 4; ++it) {
      int lr = team + (it << 3);
      int r = (h << 5) + lr;
      int j = (h << 2) + it;   // static: peR index for row r = team + j*8
      f4 a = *(const f4*)(Wl + (((lr << 9) + (c0 << 2)) ^ ((lr & 7) << 4)));
      float p0 = b2f((unsigned short)peR[j].x), p1 = b2f((unsigned short)(peR[j].x >> 16));
      float p2 = b2f((unsigned short)peR[j].y), p3 = b2f((unsigned short)(peR[j].y >> 16));
      float t0 = relu(a[0] + vb1.x) + p0;
      float t1 = relu(a[1] + vb1.y) + p1;
      float t2 = relu(a[2] + vb1.z) + p2;
      float t3 = relu(a[3] + vb1.w) + p3;
      uint2 op;
      op.x = (unsigned)f2b(t0) | ((unsigned)f2b(t1) << 16);
      op.y = (unsigned)f2b(t2) | ((unsigned)f2b(t3) << 16);
      *(uint2*)(A + (((r << 8) + (c0 << 1)) ^ ((r & 7) << 4))) = op;
    }
    __syncthreads();
  }
  stage_Wh(Wl, wt + 65536, 128, 0);   // We2T K 0..63
  __syncthreads();
  f4 acc2[2][4] = {};
  mm_h(A, Wl, wm, wn, lane, acc2, 0);
  __syncthreads();
  stage_Wh(Wl, wt + 65536, 128, 64);  // We2T K 64..127
  __syncthreads();
  mm_h(A, Wl, wm, wn, lane, acc2, 1);
  __syncthreads();
  // final epilogue: fragments -> stg (32KB f32, swizzled), then linear pass
  dump_full(stg, acc2, lane, wm, wn);
  __syncthreads();
  const float4 vb2 = *(const float4*)(be2 + c0);
#pragma unroll
  for (int it = 0; it < 8; ++it) {
    int r = team + (it << 3);
    long edge = e0 + r;
    if (edge < E) {
      f4 a = *(const f4*)(stg + (((r << 9) + (c0 << 2)) ^ ((r & 7) << 4)));
      float ev0 = relu(a[0] + vb2.x), ev1 = relu(a[1] + vb2.y);
      float ev2 = relu(a[2] + vb2.z), ev3 = relu(a[3] + vb2.w);
      float4 ov; ov.x = ev0; ov.y = ev1; ov.z = ev2; ov.w = ev3;
      *(float4*)(eout + edge * 128 + c0) = ov;
      uint2 hu = *(const uint2*)(hbf + (long)srcI[r] * 128 + c0);
      float h0 = b2f((unsigned short)hu.x), h1 = b2f((unsigned short)(hu.x >> 16));
      float h2 = b2f((unsigned short)hu.y), h3 = b2f((unsigned short)(hu.y >> 16));
      unsigned short m0 = f2b(relu(ev0 + h0)), m1 = f2b(relu(ev1 + h1));
      unsigned short m2 = f2b(relu(ev2 + h2)), m3 = f2b(relu(ev3 + h3));
      uint2 mo;
      mo.x = (unsigned int)m0 | ((unsigned int)m1 << 16);
      mo.y = (unsigned int)m2 | ((unsigned int)m3 << 16);
      *(uint2*)(msg + edge * 128 + c0) = mo;
    }
  }
}

// ---- aggregation: one wave per node, gather msg rows of in-edges (unroll 4)
__global__ __launch_bounds__(256) void k_aggr(
    const int* __restrict__ off, const int* __restrict__ deg,
    const int* __restrict__ eidx, const unsigned short* __restrict__ msg,
    float* __restrict__ aggr, long N) {
  long node = (long)blockIdx.x * 4 + (threadIdx.x >> 6);
  if (node >= N) return;
  const int lane = threadIdx.x & 63;
  int st = off[node], d = deg[node];
  float a0 = 0.f, a1 = 0.f;
  int i = 0;
  for (; i + 3 < d; i += 4) {
    int e0i = eidx[st + i], e1i = eidx[st + i + 1];
    int e2i = eidx[st + i + 2], e3i = eidx[st + i + 3];
    unsigned int u0 = *(const unsigned int*)(msg + (long)e0i * 128 + lane * 2);
    unsigned int u1 = *(const unsigned int*)(msg + (long)e1i * 128 + lane * 2);
    unsigned int u2 = *(const unsigned int*)(msg + (long)e2i * 128 + lane * 2);
    unsigned int u3 = *(const unsigned int*)(msg + (long)e3i * 128 + lane * 2);
    a0 += b2f((unsigned short)u0) + b2f((unsigned short)u1) +
          b2f((unsigned short)u2) + b2f((unsigned short)u3);
    a1 += b2f((unsigned short)(u0 >> 16)) + b2f((unsigned short)(u1 >> 16)) +
          b2f((unsigned short)(u2 >> 16)) + b2f((unsigned short)(u3 >> 16));
  }
  for (; i < d; ++i) {
    int eid = eidx[st + i];
    unsigned int u = *(const unsigned int*)(msg + (long)eid * 128 + lane * 2);
    a0 += b2f((unsigned short)u);
    a1 += b2f((unsigned short)(u >> 16));
  }
  *(float2*)(aggr + node * 128 + lane * 2) = float2{a0, a1};
}

// ---- kernel 3 (round-7 version): z=(h+V)+aggr -> @Wh,relu,+x -> @Wf1,relu -> @Wf2
__global__ __launch_bounds__(256, 2) void k_nodes2(
    const unsigned short* __restrict__ hpvb, const float* __restrict__ aggr,
    const float* __restrict__ x, const float* __restrict__ bh,
    const float* __restrict__ bf1, const float* __restrict__ bf2,
    const unsigned short* __restrict__ wt, float* __restrict__ out, long N) {
  extern __shared__ char sm[];
  char* A = sm;           // 16KB
  char* T = sm + 16384;   // 16KB
  char* Wl = sm + 32768;  // 32KB
  long n0 = (long)blockIdx.x * 64;
  const int tid = threadIdx.x;
  stage_A_mix(A, hpvb, aggr, n0, N);
  stage_W(Wl, wt + 81920, 128, 0);   // WhT
  __syncthreads();
  const int lane = tid & 63, w = tid >> 6, wm = w >> 1, wn = w & 1;
  f4 acc1[2][4] = {};
  mm(A, Wl, wm, wn, lane, acc1);
  __syncthreads();
#pragma unroll
  for (int ct = 0; ct < 4; ++ct) {
    int col = (wn << 6) + (ct << 4) + (lane & 15);
    float bb = bh[col];
#pragma unroll
    for (int rt = 0; rt < 2; ++rt)
#pragma unroll
      for (int j = 0; j < 4; ++j) {
        int rl = (wm << 5) + (rt << 4) + ((lane >> 4) << 2) + j;
        long row = n0 + rl;
        float xv = (row < N) ? x[row * 128 + col] : 0.f;
        float tv = relu(acc1[rt][ct][j] + bb) + xv;
        *(unsigned short*)(T + (((rl << 8) + (col << 1)) ^ ((rl & 7) << 4))) = f2b(tv);
      }
  }
  stage_W(Wl, wt + 98304, 128, 0);   // Wf1T rows 0..127
  __syncthreads();
  f4 accA[2][4] = {};
  mm(T, Wl, wm, wn, lane, accA);
  __syncthreads();
#pragma unroll
  for (int ct = 0; ct < 4; ++ct) {
    int col = (wn << 6) + (ct << 4) + (lane & 15);
    float bb = bf1[col];
#pragma unroll
    for (int rt = 0; rt < 2; ++rt)
#pragma unroll
      for (int j = 0; j < 4; ++j) {
        int rl = (wm << 5) + (rt << 4) + ((lane >> 4) << 2) + j;
        float uv = relu(accA[rt][ct][j] + bb);
        *(unsigned short*)(A + (((rl << 8) + (col << 1)) ^ ((rl & 7) << 4))) = f2b(uv);
      }
  }
  stage_W(Wl, wt + 131072, 256, 0);  // Wf2T k 0..127
  __syncthreads();
  f4 acc3[2][4] = {};
  mm(A, Wl, wm, wn, lane, acc3);
  __syncthreads();
  stage_W(Wl, wt + 114688, 128, 0);  // Wf1T rows 128..255
  __syncthreads();
  f4 accB[2][4] = {};
  mm(T, Wl, wm, wn, lane, accB);
  __syncthreads();
#pragma unroll
  for (int ct = 0; ct < 4; ++ct) {
    int col = (wn << 6) + (ct << 4) + (lane & 15);
    float bb = bf1[128 + col];
#pragma unroll
    for (int rt = 0; rt < 2; ++rt)
#pragma unroll
      for (int j = 0; j < 4; ++j) {
        int rl = (wm << 5) + (rt << 4) + ((lane >> 4) << 2) + j;
        float uv = relu(accB[rt][ct][j] + bb);
        *(unsigned short*)(A + (((rl << 8) + (col << 1)) ^ ((rl & 7) << 4))) = f2b(uv);
      }
  }
  stage_W(Wl, wt + 131072, 256, 128);  // Wf2T k 128..255
  __syncthreads();
  mm(A, Wl, wm, wn, lane, acc3);
#pragma unroll
  for (int ct = 0; ct < 4; ++ct) {
    int col = (wn << 6) + (ct << 4) + (lane & 15);
    float bb = bf2[col];
#pragma unroll
    for (int rt = 0; rt < 2; ++rt)
#pragma unroll
      for (int j = 0; j < 4; ++j) {
        int rl = (wm << 5) + (rt << 4) + ((lane >> 4) << 2) + j;
        long row = n0 + rl;
        if (row < N) out[row * 128 + col] = acc3[rt][ct][j] + bb;
      }
  }
}

extern "C" void kernel_launch(void* const* d_in, const int* in_sizes, int n_in,
                              void* d_out, int out_size, void* d_ws, size_t ws_size,
                              hipStream_t stream) {
  const float* x   = (const float*)d_in[0];
  const float* ph  = (const float*)d_in[1];
  const float* ea  = (const float*)d_in[2];
  const float* pe  = (const float*)d_in[3];
  const int*   ei  = (const int*)d_in[4];
  const float* Wq  = (const float*)d_in[5];  const float* bq  = (const float*)d_in[6];
  const float* Wk  = (const float*)d_in[7];  const float* bk  = (const float*)d_in[8];
  const float* Wv  = (const float*)d_in[9];  const float* bv  = (const float*)d_in[10];
  const float* We1 = (const float*)d_in[11]; const float* be1 = (const float*)d_in[12];
  const float* We2 = (const float*)d_in[13]; const float* be2 = (const float*)d_in[14];
  const float* Wh  = (const float*)d_in[15]; const float* bh  = (const float*)d_in[16];
  const float* Wf1 = (const float*)d_in[17]; const float* bf1 = (const float*)d_in[18];
  const float* Wf2 = (const float*)d_in[19]; const float* bf2 = (const float*)d_in[20];
  const long N = in_sizes[0] / 128;
  const long E = in_sizes[2] / 128;

  char* ws = (char*)d_ws;
  size_t pos_ = 0;
  auto alloc = [&](size_t bytes) { size_t p = pos_; pos_ += (bytes + 255) & ~255ULL; return p; };
  size_t o_wt   = alloc(327680);
  size_t o_hbf  = alloc((size_t)N * 256);
  size_t o_hpv  = alloc((size_t)N * 256);   // bf16
  size_t o_aggr = alloc((size_t)N * 512);
  size_t o_deg  = alloc((size_t)N * 4);
  size_t o_ex   = alloc((size_t)N * 4);
  size_t o_cur  = alloc((size_t)N * 4);
  size_t o_off  = alloc((size_t)N * 4);
  size_t o_bsum = alloc(4096);
  size_t o_eidx = alloc((size_t)E * 4);
  size_t o_msg  = alloc((size_t)E * 256);
  (void)pos_;

  unsigned short* wt   = (unsigned short*)(ws + o_wt);
  unsigned short* hbf  = (unsigned short*)(ws + o_hbf);
  unsigned short* hpvb = (unsigned short*)(ws + o_hpv);
  float* aggr = (float*)(ws + o_aggr);
  float* outH = (float*)d_out;
  float* outE = outH + N * 128;

  k_prep<<<640, 256, 0, stream>>>(Wq, Wk, Wv, We1, We2, Wh, Wf1, Wf2, wt);
  int nb = (int)((N + 63) / 64);
  int eb = (int)((E + 63) / 64);
  k_nodes1<<<nb, 256, 65536, stream>>>(x, ph, bq, bk, bv, wt, hbf, hpvb, N);

  int* deg = (int*)(ws + o_deg);
  int* ex  = (int*)(ws + o_ex);
  int* cur = (int*)(ws + o_cur);
  int* off = (int*)(ws + o_off);
  int* bsum = (int*)(ws + o_bsum);
  int* eidx = (int*)(ws + o_eidx);
  unsigned short* msg = (unsigned short*)(ws + o_msg);
  int nb1 = (int)((N + 255) / 256);
  hipMemsetAsync(deg, 0, (size_t)N * 4, stream);
  k_deg<<<(int)((E + 255) / 256), 256, 0, stream>>>(ei, deg, E);
  k_scanA<<<nb1, 256, 0, stream>>>(deg, ex, bsum, (int)N);
  k_scanB<<<1, 1024, 0, stream>>>(bsum, nb1);
  k_scanC<<<nb1, 256, 0, stream>>>(ex, bsum, off, cur, (int)N);
  k_fill<<<(int)((E + 255) / 256), 256, 0, stream>>>(ei, cur, eidx, E);
  k_edges<<<eb, 256, 33024, stream>>>(ea, pe, be1, be2, wt, ei, hbf, msg, outE, E);
  k_aggr<<<(int)((N + 3) / 4), 256, 0, stream>>>(off, deg, eidx, msg, aggr, N);
  k_nodes2<<<nb, 256, 65536, stream>>>(hpvb, aggr, x, bh, bf1, bf2, wt, outH, N);
}

// Round 10
// 557.478 us; speedup vs baseline: 1.4329x; 1.4329x over previous
//
#include <hip/hip_runtime.h>

typedef __attribute__((ext_vector_type(8))) short bfrag;   // 8 bf16 = 4 VGPRs
typedef __attribute__((ext_vector_type(4))) float f4;      // MFMA 16x16 acc

__device__ __forceinline__ unsigned short f2b(float f) {
  unsigned int u = __builtin_bit_cast(unsigned int, f);
  u = (u + 0x7fffu + ((u >> 16) & 1u)) >> 16;   // RNE f32->bf16
  return (unsigned short)u;
}
__device__ __forceinline__ float b2f(unsigned short s) {
  unsigned int u = ((unsigned int)s) << 16;
  return __builtin_bit_cast(float, u);
}
__device__ __forceinline__ float relu(float v) { return v > 0.f ? v : 0.f; }

// ---- stage a 64x128 f32 tile into LDS bf16, swizzled
__device__ __forceinline__ void stage_A(char* dst, const float* s0, long r0, long maxRow) {
  const int tid = threadIdx.x;
#pragma unroll
  for (int i = 0; i < 4; ++i) {
    int ch = tid + (i << 8);
    int row = ch >> 4, kg = ch & 15;
    long gr = r0 + row;
    float v[8];
    if (gr < maxRow) {
      const float4* p = (const float4*)(s0 + gr * 128 + kg * 8);
      float4 a = p[0], b = p[1];
      v[0] = a.x; v[1] = a.y; v[2] = a.z; v[3] = a.w;
      v[4] = b.x; v[5] = b.y; v[6] = b.z; v[7] = b.w;
    } else {
#pragma unroll
      for (int j = 0; j < 8; ++j) v[j] = 0.f;
    }
    union { unsigned short h[8]; uint4 u; } pk;
#pragma unroll
    for (int j = 0; j < 8; ++j) pk.h[j] = f2b(v[j]);
    *(uint4*)(dst + (((row << 8) + (kg << 4)) ^ ((row & 7) << 4))) = pk.u;
  }
}

// ---- stage bf16(hb) + f32(ag) sum into LDS bf16, swizzled
__device__ __forceinline__ void stage_A_mix(char* dst, const unsigned short* hb,
                                            const float* ag, long r0, long maxRow) {
  const int tid = threadIdx.x;
#pragma unroll
  for (int i = 0; i < 4; ++i) {
    int ch = tid + (i << 8);
    int row = ch >> 4, kg = ch & 15;
    long gr = r0 + row;
    union { unsigned short h[8]; uint4 u; } pk;
    if (gr < maxRow) {
      uint4 hv = *(const uint4*)(hb + gr * 128 + kg * 8);
      const float4* q = (const float4*)(ag + gr * 128 + kg * 8);
      float4 c = q[0], d = q[1];
      pk.h[0] = f2b(b2f((unsigned short)hv.x) + c.x);
      pk.h[1] = f2b(b2f((unsigned short)(hv.x >> 16)) + c.y);
      pk.h[2] = f2b(b2f((unsigned short)hv.y) + c.z);
      pk.h[3] = f2b(b2f((unsigned short)(hv.y >> 16)) + c.w);
      pk.h[4] = f2b(b2f((unsigned short)hv.z) + d.x);
      pk.h[5] = f2b(b2f((unsigned short)(hv.z >> 16)) + d.y);
      pk.h[6] = f2b(b2f((unsigned short)hv.w) + d.z);
      pk.h[7] = f2b(b2f((unsigned short)(hv.w >> 16)) + d.w);
    } else {
      pk.u = uint4{0, 0, 0, 0};
    }
    *(uint4*)(dst + (((row << 8) + (kg << 4)) ^ ((row & 7) << 4))) = pk.u;
  }
}

// ---- stage 128x128 bf16 weight tile into 32KB LDS, swizzled
__device__ __forceinline__ void stage_W(char* dst, const unsigned short* src,
                                        int rowStride, int kOff) {
  const int tid = threadIdx.x;
#pragma unroll
  for (int i = 0; i < 8; ++i) {
    int ch = tid + (i << 8);
    int col = ch >> 4, kg = ch & 15;
    uint4 u = *(const uint4*)(src + (size_t)col * rowStride + kOff + kg * 8);
    *(uint4*)(dst + (((col << 8) + (kg << 4)) ^ ((col & 7) << 4))) = u;
  }
}

// ---- stage 128col x 64K bf16 weight K-half into 16KB LDS, swizzled 128B rows
__device__ __forceinline__ void stage_Wh(char* dst, const unsigned short* src,
                                         int rowStride, int kOff) {
  const int tid = threadIdx.x;
#pragma unroll
  for (int i = 0; i < 4; ++i) {
    int ch = tid + (i << 8);
    int c = ch >> 3, kg = ch & 7;
    uint4 u = *(const uint4*)(src + (size_t)c * rowStride + kOff + kg * 8);
    *(uint4*)(dst + (((c << 7) + (kg << 4)) ^ ((c & 7) << 4))) = u;
  }
}

// ---- per-wave 32x64 tile matmul over K=128 (full-K weight tile)
__device__ __forceinline__ void mm(const char* A, const char* W, int wm, int wn,
                                   int lane, f4 acc[2][4]) {
#pragma unroll
  for (int kk = 0; kk < 4; ++kk) {
    bfrag a[2], b[4];
#pragma unroll
    for (int rt = 0; rt < 2; ++rt) {
      int row = (wm << 5) + (rt << 4) + (lane & 15);
      a[rt] = *(const bfrag*)(A + (((row << 8) + (kk << 6) + ((lane >> 4) << 4)) ^ ((row & 7) << 4)));
    }
#pragma unroll
    for (int ct = 0; ct < 4; ++ct) {
      int col = (wn << 6) + (ct << 4) + (lane & 15);
      b[ct] = *(const bfrag*)(W + (((col << 8) + (kk << 6) + ((lane >> 4) << 4)) ^ ((col & 7) << 4)));
    }
#pragma unroll
    for (int rt = 0; rt < 2; ++rt)
#pragma unroll
      for (int ct = 0; ct < 4; ++ct)
        acc[rt][ct] = __builtin_amdgcn_mfma_f32_16x16x32_bf16(a[rt], b[ct], acc[rt][ct], 0, 0, 0);
  }
}

// ---- per-wave 32x64 over one 64-wide K-half (16KB weight tile), accumulate
__device__ __forceinline__ void mm_h(const char* A, const char* W, int wm, int wn,
                                     int lane, f4 acc[2][4], int kh) {
#pragma unroll
  for (int kk2 = 0; kk2 < 2; ++kk2) {
    int kA = (kh << 1) + kk2;
    bfrag a[2], b[4];
#pragma unroll
    for (int rt = 0; rt < 2; ++rt) {
      int row = (wm << 5) + (rt << 4) + (lane & 15);
      a[rt] = *(const bfrag*)(A + (((row << 8) + (kA << 6) + ((lane >> 4) << 4)) ^ ((row & 7) << 4)));
    }
#pragma unroll
    for (int ct = 0; ct < 4; ++ct) {
      int col = (wn << 6) + (ct << 4) + (lane & 15);
      b[ct] = *(const bfrag*)(W + (((col << 7) + (kk2 << 6) + ((lane >> 4) << 4)) ^ ((col & 7) << 4)));
    }
#pragma unroll
    for (int rt = 0; rt < 2; ++rt)
#pragma unroll
      for (int ct = 0; ct < 4; ++ct)
        acc[rt][ct] = __builtin_amdgcn_mfma_f32_16x16x32_bf16(a[rt], b[ct], acc[rt][ct], 0, 0, 0);
  }
}

// ---- dump one wave's acc (rows of its wm-half) into 16KB f32 half-stage
__device__ __forceinline__ void dump_half(char* Wl, const f4 acc[2][4], int lane, int wn) {
#pragma unroll
  for (int ct = 0; ct < 4; ++ct) {
    int col = (wn << 6) + (ct << 4) + (lane & 15);
#pragma unroll
    for (int rt = 0; rt < 2; ++rt)
#pragma unroll
      for (int j = 0; j < 4; ++j) {
        int lr = (rt << 4) + ((lane >> 4) << 2) + j;
        *(float*)(Wl + (((lr << 9) + (col << 2)) ^ ((lr & 7) << 4))) = acc[rt][ct][j];
      }
  }
}

// ---- dump full 64-row acc into 32KB f32 stage
__device__ __forceinline__ void dump_full(char* stg, const f4 acc[2][4], int lane, int wm, int wn) {
#pragma unroll
  for (int ct = 0; ct < 4; ++ct) {
    int col = (wn << 6) + (ct << 4) + (lane & 15);
#pragma unroll
    for (int rt = 0; rt < 2; ++rt)
#pragma unroll
      for (int j = 0; j < 4; ++j) {
        int rl = (wm << 5) + (rt << 4) + ((lane >> 4) << 2) + j;
        *(float*)(stg + (((rl << 9) + (col << 2)) ^ ((rl & 7) << 4))) = acc[rt][ct][j];
      }
  }
}

// ---- weight prep: f32 [in][out] -> bf16 [out][in]
__global__ void k_prep(const float* __restrict__ Wq, const float* __restrict__ Wk,
                       const float* __restrict__ Wv, const float* __restrict__ We1,
                       const float* __restrict__ We2, const float* __restrict__ Wh,
                       const float* __restrict__ Wf1, const float* __restrict__ Wf2,
                       unsigned short* __restrict__ wt) {
  int b = blockIdx.x, t = threadIdx.x;
  if (b < 384) {
    int m = b >> 6;
    const float* tbl[6] = {Wq, Wk, Wv, We1, We2, Wh};
    const float* src = tbl[m];
    int local = ((b & 63) << 8) + t;
    int n = local >> 7, k = local & 127;
    wt[m * 16384 + local] = f2b(src[k * 128 + n]);
  } else if (b < 512) {
    int local = ((b - 384) << 8) + t;   // Wf1T [256][128]
    int n = local >> 7, k = local & 127;
    wt[98304 + local] = f2b(Wf1[k * 256 + n]);
  } else {
    int local = ((b - 512) << 8) + t;   // Wf2T [128][256]
    int n = local >> 8, k = local & 255;
    wt[131072 + local] = f2b(Wf2[k * 128 + n]);
  }
}

// ---- CSR build ----
__global__ void k_deg(const int* __restrict__ ei, int* __restrict__ deg, long E) {
  long g = (long)blockIdx.x * 256 + threadIdx.x;
  if (g < E) atomicAdd(deg + ei[E + g], 1);
}

__global__ void k_scanA(const int* __restrict__ deg, int* __restrict__ ex,
                        int* __restrict__ bsum, int n) {
  __shared__ int s[256];
  int t = threadIdx.x; int g = blockIdx.x * 256 + t;
  int v = (g < n) ? deg[g] : 0;
  int val = v;
  s[t] = val; __syncthreads();
#pragma unroll
  for (int o = 1; o < 256; o <<= 1) {
    int u = (t >= o) ? s[t - o] : 0;
    __syncthreads();
    val += u; s[t] = val;
    __syncthreads();
  }
  if (g < n) ex[g] = val - v;
  if (t == 255) bsum[blockIdx.x] = val;
}

__global__ void k_scanB(int* __restrict__ bsum, int nb) {
  __shared__ int s[1024];
  int t = threadIdx.x;
  int v = (t < nb) ? bsum[t] : 0;
  int val = v;
  s[t] = val; __syncthreads();
#pragma unroll
  for (int o = 1; o < 1024; o <<= 1) {
    int u = (t >= o) ? s[t - o] : 0;
    __syncthreads();
    val += u; s[t] = val;
    __syncthreads();
  }
  if (t < nb) bsum[t] = val - v;
}

__global__ void k_scanC(const int* __restrict__ ex, const int* __restrict__ bsum,
                        int* __restrict__ off, int* __restrict__ cursor, int n) {
  int g = blockIdx.x * 256 + threadIdx.x;
  if (g < n) {
    int o = ex[g] + bsum[blockIdx.x];
    off[g] = o; cursor[g] = o;
  }
}

__global__ void k_fill(const int* __restrict__ ei, int* __restrict__ cursor,
                       int* __restrict__ eidx, long E) {
  long g = (long)blockIdx.x * 256 + threadIdx.x;
  if (g < E) {
    int pos = atomicAdd(cursor + ei[E + g], 1);
    eidx[pos] = (int)g;
  }
}

// ---- kernel 1: Q,K,V -> h = relu(Q*K) (bf16), hpvb = bf16(h+V)
__global__ __launch_bounds__(256, 2) void k_nodes1(
    const float* __restrict__ x, const float* __restrict__ ph,
    const float* __restrict__ bq, const float* __restrict__ bk,
    const float* __restrict__ bv, const unsigned short* __restrict__ wt,
    unsigned short* __restrict__ hbf, unsigned short* __restrict__ hpvb, long N) {
  extern __shared__ char sm[];
  char* Ax = sm;            // 16KB (x tile, then h out)
  char* Aph = sm + 16384;   // 16KB (ph tile, then h+v out)
  char* Wl = sm + 32768;    // 32KB
  long n0 = (long)blockIdx.x * 64;
  const int tid = threadIdx.x, lane = tid & 63, w = tid >> 6, wm = w >> 1, wn = w & 1;
  const int team = tid >> 5, c0 = (tid & 31) << 2;
  stage_A(Ax, x, n0, N);
  stage_A(Aph, ph, n0, N);
  stage_W(Wl, wt + 0, 128, 0);
  __syncthreads();
  f4 accQ[2][4] = {};
  mm(Ax, Wl, wm, wn, lane, accQ);
  __syncthreads();
  stage_W(Wl, wt + 16384, 128, 0);
  __syncthreads();
  f4 accK[2][4] = {};
  mm(Aph, Wl, wm, wn, lane, accK);
  __syncthreads();
  stage_W(Wl, wt + 32768, 128, 0);
  __syncthreads();
  f4 accV[2][4] = {};
  mm(Aph, Wl, wm, wn, lane, accV);
  __syncthreads();
  // epilogue: h -> Ax (bf16 swizzled), h+v -> Aph (bf16 swizzled)
#pragma unroll
  for (int ct = 0; ct < 4; ++ct) {
    int col = (wn << 6) + (ct << 4) + (lane & 15);
    float vbq = bq[col], vbk = bk[col], vbv = bv[col];
#pragma unroll
    for (int rt = 0; rt < 2; ++rt)
#pragma unroll
      for (int j = 0; j < 4; ++j) {
        int rl = (wm << 5) + (rt << 4) + ((lane >> 4) << 2) + j;
        float q = accQ[rt][ct][j] + vbq;
        float k = accK[rt][ct][j] + vbk;
        float v = accV[rt][ct][j] + vbv;
        float h = relu(q * k);
        *(unsigned short*)(Ax + (((rl << 8) + (col << 1)) ^ ((rl & 7) << 4))) = f2b(h);
        *(unsigned short*)(Aph + (((rl << 8) + (col << 1)) ^ ((rl & 7) << 4))) = f2b(h + v);
      }
  }
  __syncthreads();
#pragma unroll
  for (int it = 0; it < 8; ++it) {
    int r = team + (it << 3);
    long row = n0 + r;
    if (row < N) {
      uint2 hb = *(const uint2*)(Ax + (((r << 8) + (c0 << 1)) ^ ((r & 7) << 4)));
      uint2 hv = *(const uint2*)(Aph + (((r << 8) + (c0 << 1)) ^ ((r & 7) << 4)));
      *(uint2*)(hbf + row * 128 + c0) = hb;
      *(uint2*)(hpvb + row * 128 + c0) = hv;
    }
  }
}

// ---- kernel 2 (measured-best): edge MLP + gather; peL/srcI in LDS, (256,3)
__global__ __launch_bounds__(256, 3) void k_edges(
    const float* __restrict__ ea, const float* __restrict__ pe,
    const float* __restrict__ be1, const float* __restrict__ be2,
    const unsigned short* __restrict__ wt, const int* __restrict__ ei,
    const unsigned short* __restrict__ hbf, unsigned short* __restrict__ msg,
    float* __restrict__ eout, long E) {
  extern __shared__ char sm[];
  char* A = sm;                                          // 16KB swizzled bf16 [64][128]
  unsigned short* peL = (unsigned short*)(sm + 16384);   // 16KB linear bf16 [64][128]
  char* Wl = sm + 32768;                                 // 16KB weight K-half / f32 half-stage
  char* stg = sm + 16384;                                // 32KB final f32 staging (peL+Wl)
  int* srcI = (int*)(sm + 49152);
  const int tid = threadIdx.x;
  const int team = tid >> 5, c0 = (tid & 31) << 2;
  long e0 = (long)blockIdx.x * 64;
  if (tid < 64) srcI[tid] = (e0 + tid < E) ? ei[e0 + tid] : 0;
  // stage A = bf16(ea+pe) swizzled; peL = bf16(pe) linear
#pragma unroll
  for (int i = 0; i < 4; ++i) {
    int ch = tid + (i << 8);
    int row = ch >> 4, kg = ch & 15;
    long gr = e0 + row;
    union { unsigned short h[8]; uint4 u; } s, q;
    if (gr < E) {
      const float4* pa = (const float4*)(ea + gr * 128 + kg * 8);
      const float4* pp = (const float4*)(pe + gr * 128 + kg * 8);
      float4 a0 = pa[0], a1 = pa[1];
      float4 p0 = pp[0], p1 = pp[1];
      s.h[0] = f2b(a0.x + p0.x); s.h[1] = f2b(a0.y + p0.y);
      s.h[2] = f2b(a0.z + p0.z); s.h[3] = f2b(a0.w + p0.w);
      s.h[4] = f2b(a1.x + p1.x); s.h[5] = f2b(a1.y + p1.y);
      s.h[6] = f2b(a1.z + p1.z); s.h[7] = f2b(a1.w + p1.w);
      q.h[0] = f2b(p0.x); q.h[1] = f2b(p0.y); q.h[2] = f2b(p0.z); q.h[3] = f2b(p0.w);
      q.h[4] = f2b(p1.x); q.h[5] = f2b(p1.y); q.h[6] = f2b(p1.z); q.h[7] = f2b(p1.w);
    } else {
      s.u = uint4{0, 0, 0, 0}; q.u = uint4{0, 0, 0, 0};
    }
    *(uint4*)((char*)peL + (row << 8) + (kg << 4)) = q.u;    // linear
    *(uint4*)(A + (((row << 8) + (kg << 4)) ^ ((row & 7) << 4))) = s.u;
  }
  stage_Wh(Wl, wt + 49152, 128, 0);   // We1T K 0..63
  __syncthreads();
  const int lane = tid & 63, w = tid >> 6, wm = w >> 1, wn = w & 1;
  f4 acc[2][4] = {};
  mm_h(A, Wl, wm, wn, lane, acc, 0);
  __syncthreads();
  stage_Wh(Wl, wt + 49152, 128, 64);  // We1T K 64..127
  __syncthreads();
  mm_h(A, Wl, wm, wn, lane, acc, 1);
  __syncthreads();
  // transition: A <- bf16(relu(acc+be1) + pe), two 32-row halves staged through Wl
  const float4 vb1 = *(const float4*)(be1 + c0);
#pragma unroll
  for (int h = 0; h < 2; ++h) {
    if (wm == h) dump_half(Wl, acc, lane, wn);
    __syncthreads();
#pragma unroll
    for (int it = 0; it < 4; ++it) {
      int lr = team + (it << 3);
      int r = (h << 5) + lr;
      f4 a = *(const f4*)(Wl + (((lr << 9) + (c0 << 2)) ^ ((lr & 7) << 4)));
      uint2 pu = *(const uint2*)(peL + (r << 7) + c0);
      float p0 = b2f((unsigned short)pu.x), p1 = b2f((unsigned short)(pu.x >> 16));
      float p2 = b2f((unsigned short)pu.y), p3 = b2f((unsigned short)(pu.y >> 16));
      unsigned short t0 = f2b(relu(a[0] + vb1.x) + p0);
      unsigned short t1 = f2b(relu(a[1] + vb1.y) + p1);
      unsigned short t2 = f2b(relu(a[2] + vb1.z) + p2);
      unsigned short t3 = f2b(relu(a[3] + vb1.w) + p3);
      uint2 op;
      op.x = (unsigned int)t0 | ((unsigned int)t1 << 16);
      op.y = (unsigned int)t2 | ((unsigned int)t3 << 16);
      *(uint2*)(A + (((r << 8) + (c0 << 1)) ^ ((r & 7) << 4))) = op;
    }
    __syncthreads();
  }
  stage_Wh(Wl, wt + 65536, 128, 0);   // We2T K 0..63
  __syncthreads();
  f4 acc2[2][4] = {};
  mm_h(A, Wl, wm, wn, lane, acc2, 0);
  __syncthreads();
  stage_Wh(Wl, wt + 65536, 128, 64);  // We2T K 64..127
  __syncthreads();
  mm_h(A, Wl, wm, wn, lane, acc2, 1);
  __syncthreads();
  // final epilogue: fragments -> stg (32KB f32, swizzled), then linear pass
  dump_full(stg, acc2, lane, wm, wn);
  __syncthreads();
  const float4 vb2 = *(const float4*)(be2 + c0);
#pragma unroll
  for (int it = 0; it < 8; ++it) {
    int r = team + (it << 3);
    long edge = e0 + r;
    if (edge < E) {
      f4 a = *(const f4*)(stg + (((r << 9) + (c0 << 2)) ^ ((r & 7) << 4)));
      float ev0 = relu(a[0] + vb2.x), ev1 = relu(a[1] + vb2.y);
      float ev2 = relu(a[2] + vb2.z), ev3 = relu(a[3] + vb2.w);
      float4 ov; ov.x = ev0; ov.y = ev1; ov.z = ev2; ov.w = ev3;
      *(float4*)(eout + edge * 128 + c0) = ov;
      uint2 hu = *(const uint2*)(hbf + (long)srcI[r] * 128 + c0);
      float h0 = b2f((unsigned short)hu.x), h1 = b2f((unsigned short)(hu.x >> 16));
      float h2 = b2f((unsigned short)hu.y), h3 = b2f((unsigned short)(hu.y >> 16));
      unsigned short m0 = f2b(relu(ev0 + h0)), m1 = f2b(relu(ev1 + h1));
      unsigned short m2 = f2b(relu(ev2 + h2)), m3 = f2b(relu(ev3 + h3));
      uint2 mo;
      mo.x = (unsigned int)m0 | ((unsigned int)m1 << 16);
      mo.y = (unsigned int)m2 | ((unsigned int)m3 << 16);
      *(uint2*)(msg + edge * 128 + c0) = mo;
    }
  }
}

// ---- aggregation: one wave per node, gather msg rows of in-edges (unroll 4)
__global__ __launch_bounds__(256) void k_aggr(
    const int* __restrict__ off, const int* __restrict__ deg,
    const int* __restrict__ eidx, const unsigned short* __restrict__ msg,
    float* __restrict__ aggr, long N) {
  long node = (long)blockIdx.x * 4 + (threadIdx.x >> 6);
  if (node >= N) return;
  const int lane = threadIdx.x & 63;
  int st = off[node], d = deg[node];
  float a0 = 0.f, a1 = 0.f;
  int i = 0;
  for (; i + 3 < d; i += 4) {
    int e0i = eidx[st + i], e1i = eidx[st + i + 1];
    int e2i = eidx[st + i + 2], e3i = eidx[st + i + 3];
    unsigned int u0 = *(const unsigned int*)(msg + (long)e0i * 128 + lane * 2);
    unsigned int u1 = *(const unsigned int*)(msg + (long)e1i * 128 + lane * 2);
    unsigned int u2 = *(const unsigned int*)(msg + (long)e2i * 128 + lane * 2);
    unsigned int u3 = *(const unsigned int*)(msg + (long)e3i * 128 + lane * 2);
    a0 += b2f((unsigned short)u0) + b2f((unsigned short)u1) +
          b2f((unsigned short)u2) + b2f((unsigned short)u3);
    a1 += b2f((unsigned short)(u0 >> 16)) + b2f((unsigned short)(u1 >> 16)) +
          b2f((unsigned short)(u2 >> 16)) + b2f((unsigned short)(u3 >> 16));
  }
  for (; i < d; ++i) {
    int eid = eidx[st + i];
    unsigned int u = *(const unsigned int*)(msg + (long)eid * 128 + lane * 2);
    a0 += b2f((unsigned short)u);
    a1 += b2f((unsigned short)(u >> 16));
  }
  *(float2*)(aggr + node * 128 + lane * 2) = float2{a0, a1};
}

// ---- kernel 3: z=(h+V)+aggr -> @Wh,relu,+x -> @Wf1,relu -> @Wf2 -> h_out
__global__ __launch_bounds__(256, 2) void k_nodes2(
    const unsigned short* __restrict__ hpvb, const float* __restrict__ aggr,
    const float* __restrict__ x, const float* __restrict__ bh,
    const float* __restrict__ bf1, const float* __restrict__ bf2,
    const unsigned short* __restrict__ wt, float* __restrict__ out, long N) {
  extern __shared__ char sm[];
  char* A = sm;           // 16KB
  char* T = sm + 16384;   // 16KB
  char* Wl = sm + 32768;  // 32KB
  long n0 = (long)blockIdx.x * 64;
  const int tid = threadIdx.x;
  stage_A_mix(A, hpvb, aggr, n0, N);
  stage_W(Wl, wt + 81920, 128, 0);   // WhT
  __syncthreads();
  const int lane = tid & 63, w = tid >> 6, wm = w >> 1, wn = w & 1;
  f4 acc1[2][4] = {};
  mm(A, Wl, wm, wn, lane, acc1);
  __syncthreads();
#pragma unroll
  for (int ct = 0; ct < 4; ++ct) {
    int col = (wn << 6) + (ct << 4) + (lane & 15);
    float bb = bh[col];
#pragma unroll
    for (int rt = 0; rt < 2; ++rt)
#pragma unroll
      for (int j = 0; j < 4; ++j) {
        int rl = (wm << 5) + (rt << 4) + ((lane >> 4) << 2) + j;
        long row = n0 + rl;
        float xv = (row < N) ? x[row * 128 + col] : 0.f;
        float tv = relu(acc1[rt][ct][j] + bb) + xv;
        *(unsigned short*)(T + (((rl << 8) + (col << 1)) ^ ((rl & 7) << 4))) = f2b(tv);
      }
  }
  stage_W(Wl, wt + 98304, 128, 0);   // Wf1T rows 0..127
  __syncthreads();
  f4 accA[2][4] = {};
  mm(T, Wl, wm, wn, lane, accA);
  __syncthreads();
#pragma unroll
  for (int ct = 0; ct < 4; ++ct) {
    int col = (wn << 6) + (ct << 4) + (lane & 15);
    float bb = bf1[col];
#pragma unroll
    for (int rt = 0; rt < 2; ++rt)
#pragma unroll
      for (int j = 0; j < 4; ++j) {
        int rl = (wm << 5) + (rt << 4) + ((lane >> 4) << 2) + j;
        float uv = relu(accA[rt][ct][j] + bb);
        *(unsigned short*)(A + (((rl << 8) + (col << 1)) ^ ((rl & 7) << 4))) = f2b(uv);
      }
  }
  stage_W(Wl, wt + 131072, 256, 0);  // Wf2T k 0..127
  __syncthreads();
  f4 acc3[2][4] = {};
  mm(A, Wl, wm, wn, lane, acc3);
  __syncthreads();
  stage_W(Wl, wt + 114688, 128, 0);  // Wf1T rows 128..255
  __syncthreads();
  f4 accB[2][4] = {};
  mm(T, Wl, wm, wn, lane, accB);
  __syncthreads();
#pragma unroll
  for (int ct = 0; ct < 4; ++ct) {
    int col = (wn << 6) + (ct << 4) + (lane & 15);
    float bb = bf1[128 + col];
#pragma unroll
    for (int rt = 0; rt < 2; ++rt)
#pragma unroll
      for (int j = 0; j < 4; ++j) {
        int rl = (wm << 5) + (rt << 4) + ((lane >> 4) << 2) + j;
        float uv = relu(accB[rt][ct][j] + bb);
        *(unsigned short*)(A + (((rl << 8) + (col << 1)) ^ ((rl & 7) << 4))) = f2b(uv);
      }
  }
  stage_W(Wl, wt + 131072, 256, 128);  // Wf2T k 128..255
  __syncthreads();
  mm(A, Wl, wm, wn, lane, acc3);
#pragma unroll
  for (int ct = 0; ct < 4; ++ct) {
    int col = (wn << 6) + (ct << 4) + (lane & 15);
    float bb = bf2[col];
#pragma unroll
    for (int rt = 0; rt < 2; ++rt)
#pragma unroll
      for (int j = 0; j < 4; ++j) {
        int rl = (wm << 5) + (rt << 4) + ((lane >> 4) << 2) + j;
        long row = n0 + rl;
        if (row < N) out[row * 128 + col] = acc3[rt][ct][j] + bb;
      }
  }
}

extern "C" void kernel_launch(void* const* d_in, const int* in_sizes, int n_in,
                              void* d_out, int out_size, void* d_ws, size_t ws_size,
                              hipStream_t stream) {
  const float* x   = (const float*)d_in[0];
  const float* ph  = (const float*)d_in[1];
  const float* ea  = (const float*)d_in[2];
  const float* pe  = (const float*)d_in[3];
  const int*   ei  = (const int*)d_in[4];
  const float* Wq  = (const float*)d_in[5];  const float* bq  = (const float*)d_in[6];
  const float* Wk  = (const float*)d_in[7];  const float* bk  = (const float*)d_in[8];
  const float* Wv  = (const float*)d_in[9];  const float* bv  = (const float*)d_in[10];
  const float* We1 = (const float*)d_in[11]; const float* be1 = (const float*)d_in[12];
  const float* We2 = (const float*)d_in[13]; const float* be2 = (const float*)d_in[14];
  const float* Wh  = (const float*)d_in[15]; const float* bh  = (const float*)d_in[16];
  const float* Wf1 = (const float*)d_in[17]; const float* bf1 = (const float*)d_in[18];
  const float* Wf2 = (const float*)d_in[19]; const float* bf2 = (const float*)d_in[20];
  const long N = in_sizes[0] / 128;
  const long E = in_sizes[2] / 128;

  char* ws = (char*)d_ws;
  size_t pos_ = 0;
  auto alloc = [&](size_t bytes) { size_t p = pos_; pos_ += (bytes + 255) & ~255ULL; return p; };
  size_t o_wt   = alloc(327680);
  size_t o_hbf  = alloc((size_t)N * 256);
  size_t o_hpv  = alloc((size_t)N * 256);   // bf16
  size_t o_aggr = alloc((size_t)N * 512);
  size_t o_deg  = alloc((size_t)N * 4);
  size_t o_ex   = alloc((size_t)N * 4);
  size_t o_cur  = alloc((size_t)N * 4);
  size_t o_off  = alloc((size_t)N * 4);
  size_t o_bsum = alloc(4096);
  size_t o_eidx = alloc((size_t)E * 4);
  size_t o_msg  = alloc((size_t)E * 256);
  (void)pos_;

  unsigned short* wt   = (unsigned short*)(ws + o_wt);
  unsigned short* hbf  = (unsigned short*)(ws + o_hbf);
  unsigned short* hpvb = (unsigned short*)(ws + o_hpv);
  float* aggr = (float*)(ws + o_aggr);
  float* outH = (float*)d_out;
  float* outE = outH + N * 128;

  k_prep<<<640, 256, 0, stream>>>(Wq, Wk, Wv, We1, We2, Wh, Wf1, Wf2, wt);
  int nb = (int)((N + 63) / 64);
  int eb = (int)((E + 63) / 64);
  k_nodes1<<<nb, 256, 65536, stream>>>(x, ph, bq, bk, bv, wt, hbf, hpvb, N);

  int* deg = (int*)(ws + o_deg);
  int* ex  = (int*)(ws + o_ex);
  int* cur = (int*)(ws + o_cur);
  int* off = (int*)(ws + o_off);
  int* bsum = (int*)(ws + o_bsum);
  int* eidx = (int*)(ws + o_eidx);
  unsigned short* msg = (unsigned short*)(ws + o_msg);
  int nb1 = (int)((N + 255) / 256);
  hipMemsetAsync(deg, 0, (size_t)N * 4, stream);
  k_deg<<<(int)((E + 255) / 256), 256, 0, stream>>>(ei, deg, E);
  k_scanA<<<nb1, 256, 0, stream>>>(deg, ex, bsum, (int)N);
  k_scanB<<<1, 1024, 0, stream>>>(bsum, nb1);
  k_scanC<<<nb1, 256, 0, stream>>>(ex, bsum, off, cur, (int)N);
  k_fill<<<(int)((E + 255) / 256), 256, 0, stream>>>(ei, cur, eidx, E);
  k_edges<<<eb, 256, 49408, stream>>>(ea, pe, be1, be2, wt, ei, hbf, msg, outE, E);
  k_aggr<<<(int)((N + 3) / 4), 256, 0, stream>>>(off, deg, eidx, msg, aggr, N);
  k_nodes2<<<nb, 256, 65536, stream>>>(hpvb, aggr, x, bh, bf1, bf2, wt, outH, N);
}